// Round 1
// baseline (474.114 us; speedup 1.0000x reference)
//
#include <hip/hip_runtime.h>

#define N_ROWS 32768
#define D_DIM  512
#define P_DIM  4096

#define OUT_XN     0
#define OUT_LOGITS (32768LL * 512)
#define OUT_CVAE   (32768LL * 512 + 32768LL * 4096)
#define OUT_PROT   (OUT_CVAE + 1)

typedef __attribute__((ext_vector_type(8))) short short8;
typedef __attribute__((ext_vector_type(4))) float f32x4;

__device__ __forceinline__ unsigned short f2bf(float f) {
  unsigned u = __float_as_uint(f);
  u = (u + 0x7FFFu + ((u >> 16) & 1u)) >> 16;
  return (unsigned short)u;
}

__device__ __forceinline__ void gload16(const void* g, void* l) {
  __builtin_amdgcn_global_load_lds((const __attribute__((address_space(1))) void*)g,
                                   (__attribute__((address_space(3))) void*)l,
                                   16, 0, 0);
}

// ---------------------------------------------------------------------------
// Prep: per-row sum of squares; NORM=1 -> write xn fp32 + bf16; NORM=0 ->
// write bf16 of raw row + |row|^2. One wave per row, 8 floats per lane.
// ---------------------------------------------------------------------------
template <int NORM>
__global__ __launch_bounds__(256) void prep_kernel(const float* __restrict__ in,
                                                   float* __restrict__ outf,
                                                   unsigned short* __restrict__ outb,
                                                   float* __restrict__ n2) {
  int wave = threadIdx.x >> 6, lane = threadIdx.x & 63;
  int row  = blockIdx.x * 4 + wave;
  const float* p = in + (size_t)row * D_DIM + lane * 8;
  float4 v0 = *(const float4*)p;
  float4 v1 = *(const float4*)(p + 4);
  float ss = v0.x*v0.x + v0.y*v0.y + v0.z*v0.z + v0.w*v0.w
           + v1.x*v1.x + v1.y*v1.y + v1.z*v1.z + v1.w*v1.w;
#pragma unroll
  for (int m = 1; m < 64; m <<= 1) ss += __shfl_xor(ss, m);
  if (NORM) {
    float rinv = 1.0f / fmaxf(sqrtf(ss), 1e-12f);
    v0.x *= rinv; v0.y *= rinv; v0.z *= rinv; v0.w *= rinv;
    v1.x *= rinv; v1.y *= rinv; v1.z *= rinv; v1.w *= rinv;
    float4* q = (float4*)(outf + (size_t)row * D_DIM + lane * 8);
    q[0] = v0; q[1] = v1;
  } else {
    if (lane == 0) n2[row] = ss;
  }
  uint4 b;
  b.x = (unsigned)f2bf(v0.x) | ((unsigned)f2bf(v0.y) << 16);
  b.y = (unsigned)f2bf(v0.z) | ((unsigned)f2bf(v0.w) << 16);
  b.z = (unsigned)f2bf(v1.x) | ((unsigned)f2bf(v1.y) << 16);
  b.w = (unsigned)f2bf(v1.z) | ((unsigned)f2bf(v1.w) << 16);
  *(uint4*)(outb + (size_t)row * D_DIM + lane * 8) = b;
}

// ---------------------------------------------------------------------------
// Fused GEMM: C = A(bf16 xn) @ B(bf16 W)^T, 128x128 tile, BK=32, 4 waves.
// Epilogue: write fp32 logits; d2 = max(1 + |W_j|^2 - 2*logit, 0); per-tile
// row-min / col-min partials to workspace.
// ---------------------------------------------------------------------------
__global__ __launch_bounds__(256) void gemm_fused(
    const unsigned short* __restrict__ A, const unsigned short* __restrict__ B,
    const float* __restrict__ w2, float* __restrict__ Cout,
    float* __restrict__ row_part, float* __restrict__ col_part) {
  __shared__ __align__(16) unsigned short As[128 * 32];
  __shared__ __align__(16) unsigned short Bs[128 * 32];
  __shared__ unsigned int rowmin_u[128];
  __shared__ unsigned int colmin_u[128];

  const int tid = threadIdx.x;
  const int wave = tid >> 6, lane = tid & 63;
  const int q = lane >> 4, r16 = lane & 15;
  const int wr = wave >> 1, wc = wave & 1;

  // XCD-aware swizzle: 8192 blocks, 1024 per XCD (bijective since 8192%8==0).
  int bid = blockIdx.x;
  int swz = ((bid & 7) << 10) | (bid >> 3);
  const int tm = swz >> 5;          // 0..255
  const int tn = swz & 31;          // 0..31
  const int row0 = tm * 128, col0 = tn * 128;

  if (tid < 128) { rowmin_u[tid] = 0x7F800000u; colmin_u[tid] = 0x7F800000u; }

  f32x4 acc[4][4];
#pragma unroll
  for (int m = 0; m < 4; ++m)
#pragma unroll
    for (int n = 0; n < 4; ++n) acc[m][n] = (f32x4){0.f, 0.f, 0.f, 0.f};

  const int k8 = q * 8;

  for (int ks = 0; ks < 16; ++ks) {
    const int k0 = ks * 32;
    // Stage 8 KB A-tile + 8 KB B-tile, 16B/lane chunks. chunk c -> row c>>2,
    // k-part (c&3)*8; LDS linear so dest = base + lane*16 (HW requirement).
#pragma unroll
    for (int i = 0; i < 2; ++i) {
      int bc = (wave + 4 * i) * 64;        // wave-uniform base chunk
      int c = bc + lane;
      int trow = c >> 2, kq = (c & 3) * 8;
      gload16(A + (size_t)(row0 + trow) * D_DIM + k0 + kq, As + bc * 8);
      gload16(B + (size_t)(col0 + trow) * D_DIM + k0 + kq, Bs + bc * 8);
    }
    __syncthreads();
    short8 af[4], bfr[4];
#pragma unroll
    for (int m = 0; m < 4; ++m)
      af[m] = *(const short8*)&As[(wr * 64 + m * 16 + r16) * 32 + k8];
#pragma unroll
    for (int n = 0; n < 4; ++n)
      bfr[n] = *(const short8*)&Bs[(wc * 64 + n * 16 + r16) * 32 + k8];
#pragma unroll
    for (int m = 0; m < 4; ++m)
#pragma unroll
      for (int n = 0; n < 4; ++n)
        acc[m][n] = __builtin_amdgcn_mfma_f32_16x16x32_bf16(af[m], bfr[n], acc[m][n], 0, 0, 0);
    __syncthreads();
  }

  // ---- epilogue ----
  float w2c[4];
#pragma unroll
  for (int n = 0; n < 4; ++n) w2c[n] = w2[col0 + wc * 64 + n * 16 + r16];

  float rmin[4][4], cmin[4];
#pragma unroll
  for (int m = 0; m < 4; ++m)
#pragma unroll
    for (int j = 0; j < 4; ++j) rmin[m][j] = 1e30f;
#pragma unroll
  for (int n = 0; n < 4; ++n) cmin[n] = 1e30f;

#pragma unroll
  for (int m = 0; m < 4; ++m) {
    int grow = row0 + wr * 64 + m * 16 + q * 4;
#pragma unroll
    for (int n = 0; n < 4; ++n) {
      int gcol = col0 + wc * 64 + n * 16 + r16;
      f32x4 c = acc[m][n];
#pragma unroll
      for (int j = 0; j < 4; ++j) {
        float v = c[j];
        Cout[(size_t)(grow + j) * P_DIM + gcol] = v;
        float d2 = fmaxf(fmaf(-2.0f, v, 1.0f + w2c[n]), 0.0f);
        rmin[m][j] = fminf(rmin[m][j], d2);
        cmin[n] = fminf(cmin[n], d2);
      }
    }
  }
  // reduce row mins across the 16 lanes of each quarter (same rows per quarter)
#pragma unroll
  for (int mask = 1; mask <= 8; mask <<= 1)
#pragma unroll
    for (int m = 0; m < 4; ++m)
#pragma unroll
      for (int j = 0; j < 4; ++j)
        rmin[m][j] = fminf(rmin[m][j], __shfl_xor(rmin[m][j], mask));
  if (r16 == 0) {
#pragma unroll
    for (int m = 0; m < 4; ++m)
#pragma unroll
      for (int j = 0; j < 4; ++j)
        atomicMin(&rowmin_u[wr * 64 + m * 16 + q * 4 + j], __float_as_uint(rmin[m][j]));
  }
  // reduce col mins across quarters (same cols for equal lane&15)
#pragma unroll
  for (int mask = 16; mask <= 32; mask <<= 1)
#pragma unroll
    for (int n = 0; n < 4; ++n)
      cmin[n] = fminf(cmin[n], __shfl_xor(cmin[n], mask));
  if (q == 0) {
#pragma unroll
    for (int n = 0; n < 4; ++n)
      atomicMin(&colmin_u[wc * 64 + n * 16 + r16], __float_as_uint(cmin[n]));
  }
  __syncthreads();
  if (tid < 128) {
    row_part[(size_t)tn * N_ROWS + row0 + tid] = __uint_as_float(rowmin_u[tid]);
    col_part[(size_t)tm * P_DIM + col0 + tid] = __uint_as_float(colmin_u[tid]);
  }
}

// ---------------------------------------------------------------------------
// For each item: min over nparts partials, sqrt, block-sum -> out[block].
// ---------------------------------------------------------------------------
__global__ __launch_bounds__(256) void minsqrt_sum(const float* __restrict__ part,
                                                   int nparts, int stride,
                                                   float* __restrict__ out) {
  int idx = blockIdx.x * 256 + threadIdx.x;
  float m = 1e30f;
  for (int p = 0; p < nparts; ++p) m = fminf(m, part[(size_t)p * stride + idx]);
  float s = sqrtf(m);
#pragma unroll
  for (int mask = 1; mask < 64; mask <<= 1) s += __shfl_xor(s, mask);
  __shared__ float wsum[4];
  int wave = threadIdx.x >> 6, lane = threadIdx.x & 63;
  if (lane == 0) wsum[wave] = s;
  __syncthreads();
  if (threadIdx.x == 0) out[blockIdx.x] = wsum[0] + wsum[1] + wsum[2] + wsum[3];
}

__global__ void finalize_kernel(const float* __restrict__ rowp, const float* __restrict__ colp,
                                const float* __restrict__ recon, const float* __restrict__ kl,
                                const float* __restrict__ mmd, float* __restrict__ out) {
  int lane = threadIdx.x;  // 64 threads
  float rs = rowp[lane] + rowp[lane + 64];
  float cs = (lane < 16) ? colp[lane] : 0.0f;
#pragma unroll
  for (int mask = 1; mask < 64; mask <<= 1) {
    rs += __shfl_xor(rs, mask);
    cs += __shfl_xor(cs, mask);
  }
  if (lane == 0) {
    out[OUT_CVAE] = recon[0] + 0.5f * kl[0] + mmd[0];
    out[OUT_PROT] = 0.5f * (rs / (float)N_ROWS) + 0.5f * (cs / (float)P_DIM);
  }
}

extern "C" void kernel_launch(void* const* d_in, const int* in_sizes, int n_in,
                              void* d_out, int out_size, void* d_ws, size_t ws_size,
                              hipStream_t stream) {
  const float* x     = (const float*)d_in[0];
  const float* W     = (const float*)d_in[1];
  const float* recon = (const float*)d_in[2];
  const float* kl    = (const float*)d_in[3];
  const float* mmd   = (const float*)d_in[4];
  float* out    = (float*)d_out;
  float* xn     = out + OUT_XN;
  float* logits = out + OUT_LOGITS;

  char* ws = (char*)d_ws;
  unsigned short* Abf = (unsigned short*)ws;                    // 33,554,432 B
  unsigned short* Bbf = (unsigned short*)(ws + 33554432);       //  4,194,304 B
  float* w2       = (float*)(ws + 37748736);                    //     16,384 B
  float* row_part = (float*)(ws + 37765120);                    //  4,194,304 B
  float* col_part = (float*)(ws + 41959424);                    //  4,194,304 B
  float* rowsums  = (float*)(ws + 46153728);                    //        512 B
  float* colsums  = (float*)(ws + 46154240);                    //         64 B

  prep_kernel<1><<<N_ROWS / 4, 256, 0, stream>>>(x, xn, Abf, nullptr);
  prep_kernel<0><<<P_DIM / 4, 256, 0, stream>>>(W, nullptr, Bbf, w2);
  gemm_fused<<<(N_ROWS / 128) * (P_DIM / 128), 256, 0, stream>>>(
      Abf, Bbf, w2, logits, row_part, col_part);
  minsqrt_sum<<<N_ROWS / 256, 256, 0, stream>>>(row_part, 32, N_ROWS, rowsums);
  minsqrt_sum<<<P_DIM / 256, 256, 0, stream>>>(col_part, 256, P_DIM, colsums);
  finalize_kernel<<<1, 64, 0, stream>>>(rowsums, colsums, recon, kl, mmd, out);
}

// Round 2
// 377.581 us; speedup vs baseline: 1.2557x; 1.2557x over previous
//
#include <hip/hip_runtime.h>

#define N_ROWS 32768
#define D_DIM  512
#define P_DIM  4096

#define OUT_LOGITS (32768LL * 512)
#define OUT_CVAE   (OUT_LOGITS + 32768LL * 4096)
#define OUT_PROT   (OUT_CVAE + 1)

typedef __attribute__((ext_vector_type(8))) short short8;
typedef __attribute__((ext_vector_type(4))) float f32x4;

__device__ __forceinline__ unsigned short f2bf(float f) {
  unsigned u = __float_as_uint(f);
  u = (u + 0x7FFFu + ((u >> 16) & 1u)) >> 16;
  return (unsigned short)u;
}

__device__ __forceinline__ void gload16(const void* g, void* l) {
  __builtin_amdgcn_global_load_lds((const __attribute__((address_space(1))) void*)g,
                                   (__attribute__((address_space(3))) void*)l,
                                   16, 0, 0);
}

// ---------------------------------------------------------------------------
// Prep: row L2-norm stats; writes bf16 copy in MFMA-fragment-major tiled
// layout: elem[(tile*8+kt)*16384 + ((ks*16+m)*64 + kq*16 + lrow)*8 + (k&7)]
// where row = tile*256 + m*16 + lrow, k = kt*64 + ks*32 + kq*8 + (k&7).
// One wave per row; lane j holds k = j*8..j*8+7 -> kt=j>>3, ks=(j>>2)&1, kq=j&3.
// ---------------------------------------------------------------------------
template <int NORM>
__global__ __launch_bounds__(256) void prep_kernel(const float* __restrict__ in,
                                                   float* __restrict__ outf,
                                                   unsigned short* __restrict__ outb,
                                                   float* __restrict__ n2) {
  int wave = threadIdx.x >> 6, lane = threadIdx.x & 63;
  int row  = blockIdx.x * 4 + wave;
  const float* p = in + (size_t)row * D_DIM + lane * 8;
  float4 v0 = *(const float4*)p;
  float4 v1 = *(const float4*)(p + 4);
  float ss = v0.x*v0.x + v0.y*v0.y + v0.z*v0.z + v0.w*v0.w
           + v1.x*v1.x + v1.y*v1.y + v1.z*v1.z + v1.w*v1.w;
#pragma unroll
  for (int m = 1; m < 64; m <<= 1) ss += __shfl_xor(ss, m);
  if (NORM) {
    float rinv = 1.0f / fmaxf(sqrtf(ss), 1e-12f);
    v0.x *= rinv; v0.y *= rinv; v0.z *= rinv; v0.w *= rinv;
    v1.x *= rinv; v1.y *= rinv; v1.z *= rinv; v1.w *= rinv;
    float4* qp = (float4*)(outf + (size_t)row * D_DIM + lane * 8);
    qp[0] = v0; qp[1] = v1;
  } else {
    if (lane == 0) n2[row] = ss;
  }
  uint4 b;
  b.x = (unsigned)f2bf(v0.x) | ((unsigned)f2bf(v0.y) << 16);
  b.y = (unsigned)f2bf(v0.z) | ((unsigned)f2bf(v0.w) << 16);
  b.z = (unsigned)f2bf(v1.x) | ((unsigned)f2bf(v1.y) << 16);
  b.w = (unsigned)f2bf(v1.z) | ((unsigned)f2bf(v1.w) << 16);
  int tile = row >> 8, mloc = (row >> 4) & 15, lrow = row & 15;
  size_t dst = ((size_t)(tile * 8 + (lane >> 3)) << 14)
             + (size_t)((((((lane >> 2) & 1) * 16 + mloc) * 64) + (lane & 3) * 16 + lrow) * 8);
  *(uint4*)(outb + dst) = b;
}

// ---------------------------------------------------------------------------
// 256x256-tile GEMM, BK=64, 8 waves (2Mx4N), double-buffered LDS (128 KiB),
// counted-vmcnt pipeline, 4 phases/K-tile, fragment-major LDS (conflict-free).
// Epilogue: fp32 logits + fused row/col min of d2 = 1 + |W_j|^2 - 2*logit.
// ---------------------------------------------------------------------------
__global__ __launch_bounds__(512) void gemm_fused(
    const unsigned short* __restrict__ A, const unsigned short* __restrict__ B,
    const float* __restrict__ w2, float* __restrict__ Cout,
    float* __restrict__ row_part, float* __restrict__ col_part) {
  __shared__ __align__(16) unsigned short As[2][16384];
  __shared__ __align__(16) unsigned short Bs[2][16384];
  __shared__ unsigned int rowmin_u[256];
  __shared__ unsigned int colmin_u[256];

  const int tid = threadIdx.x;
  const int wave = tid >> 6, lane = tid & 63;
  const int q = lane >> 4, r16 = lane & 15;
  const int wr = wave >> 2, wc = wave & 3;

  int bid = blockIdx.x;
  int swz = ((bid & 7) << 8) | (bid >> 3);          // bijective: 2048 % 8 == 0
  const int tm = swz >> 4, tn = swz & 15;
  const int row0 = tm * 256, col0 = tn * 256;

  if (tid < 256) { rowmin_u[tid] = 0x7F800000u; colmin_u[tid] = 0x7F800000u; }

  const unsigned short* Abase = A + ((size_t)tm << 17);   // tm * 8 * 16384
  const unsigned short* Bbase = B + ((size_t)tn << 17);

  f32x4 acc[8][4];
#pragma unroll
  for (int m = 0; m < 8; ++m)
#pragma unroll
    for (int n = 0; n < 4; ++n) acc[m][n] = (f32x4){0.f, 0.f, 0.f, 0.f};

  auto stage = [&](int kt, int nb) {
    const unsigned short* ag = Abase + ((size_t)kt << 14);
    const unsigned short* bg = Bbase + ((size_t)kt << 14);
    unsigned short* al = &As[nb][0];
    unsigned short* bl = &Bs[nb][0];
#pragma unroll
    for (int i = 0; i < 4; ++i) {
      int c = tid + 512 * i;                 // lane-linear: wave base + lane
      gload16(ag + c * 8, al + c * 8);
      gload16(bg + c * 8, bl + c * 8);
    }
  };

  stage(0, 0);
  stage(1, 1);

  short8 afr[2][8];   // [ks][m]
  short8 bfr[2][4];   // [ks][n]
  int cur = 0;

  for (int kt = 0; kt < 8; ++kt) {
    if (kt < 7) { asm volatile("s_waitcnt vmcnt(8)" ::: "memory"); }
    else        { asm volatile("s_waitcnt vmcnt(0)" ::: "memory"); }
    __builtin_amdgcn_sched_barrier(0);
    __builtin_amdgcn_s_barrier();
    __builtin_amdgcn_sched_barrier(0);
    const unsigned short* al = &As[cur][0];
    const unsigned short* bl = &Bs[cur][0];

    // ---- phase 0: read A m0-3 (both ks) + B n0-1; MFMA (m0-3 x n0-1) ----
#pragma unroll
    for (int ks = 0; ks < 2; ++ks) {
#pragma unroll
      for (int m = 0; m < 4; ++m)
        afr[ks][m] = *(const short8*)(al + ((ks * 16 + wr * 8 + m) * 64 + lane) * 8);
#pragma unroll
      for (int n = 0; n < 2; ++n)
        bfr[ks][n] = *(const short8*)(bl + ((ks * 16 + wc * 4 + n) * 64 + lane) * 8);
    }
    __builtin_amdgcn_sched_barrier(0);
    __builtin_amdgcn_s_barrier();
    __builtin_amdgcn_s_setprio(1);
#pragma unroll
    for (int m = 0; m < 4; ++m)
#pragma unroll
      for (int n = 0; n < 2; ++n)
#pragma unroll
        for (int ks = 0; ks < 2; ++ks)
          acc[m][n] = __builtin_amdgcn_mfma_f32_16x16x32_bf16(afr[ks][m], bfr[ks][n], acc[m][n], 0, 0, 0);
    __builtin_amdgcn_s_setprio(0);
    __builtin_amdgcn_sched_barrier(0);
    __builtin_amdgcn_s_barrier();
    __builtin_amdgcn_sched_barrier(0);

    // ---- phase 1: read B n2-3; MFMA (m0-3 x n2-3) ----
#pragma unroll
    for (int ks = 0; ks < 2; ++ks)
#pragma unroll
      for (int n = 2; n < 4; ++n)
        bfr[ks][n] = *(const short8*)(bl + ((ks * 16 + wc * 4 + n) * 64 + lane) * 8);
    __builtin_amdgcn_sched_barrier(0);
    __builtin_amdgcn_s_barrier();
    __builtin_amdgcn_s_setprio(1);
#pragma unroll
    for (int m = 0; m < 4; ++m)
#pragma unroll
      for (int n = 2; n < 4; ++n)
#pragma unroll
        for (int ks = 0; ks < 2; ++ks)
          acc[m][n] = __builtin_amdgcn_mfma_f32_16x16x32_bf16(afr[ks][m], bfr[ks][n], acc[m][n], 0, 0, 0);
    __builtin_amdgcn_s_setprio(0);
    __builtin_amdgcn_sched_barrier(0);
    __builtin_amdgcn_s_barrier();
    __builtin_amdgcn_sched_barrier(0);

    // ---- phase 2: read A m4-7; MFMA (m4-7 x n0-1) ----
#pragma unroll
    for (int ks = 0; ks < 2; ++ks)
#pragma unroll
      for (int m = 4; m < 8; ++m)
        afr[ks][m] = *(const short8*)(al + ((ks * 16 + wr * 8 + m) * 64 + lane) * 8);
    __builtin_amdgcn_sched_barrier(0);
    __builtin_amdgcn_s_barrier();
    __builtin_amdgcn_s_setprio(1);
#pragma unroll
    for (int m = 4; m < 8; ++m)
#pragma unroll
      for (int n = 0; n < 2; ++n)
#pragma unroll
        for (int ks = 0; ks < 2; ++ks)
          acc[m][n] = __builtin_amdgcn_mfma_f32_16x16x32_bf16(afr[ks][m], bfr[ks][n], acc[m][n], 0, 0, 0);
    __builtin_amdgcn_s_setprio(0);
    asm volatile("s_waitcnt lgkmcnt(0)" ::: "memory");   // all buf[cur] reads landed
    __builtin_amdgcn_sched_barrier(0);
    __builtin_amdgcn_s_barrier();
    __builtin_amdgcn_sched_barrier(0);

    // ---- phase 3: prefetch kt+2 into buf[cur] (reads done); MFMA (m4-7 x n2-3)
    if (kt < 6) stage(kt + 2, cur);
    __builtin_amdgcn_sched_barrier(0);
    __builtin_amdgcn_s_barrier();
    __builtin_amdgcn_s_setprio(1);
#pragma unroll
    for (int m = 4; m < 8; ++m)
#pragma unroll
      for (int n = 2; n < 4; ++n)
#pragma unroll
        for (int ks = 0; ks < 2; ++ks)
          acc[m][n] = __builtin_amdgcn_mfma_f32_16x16x32_bf16(afr[ks][m], bfr[ks][n], acc[m][n], 0, 0, 0);
    __builtin_amdgcn_s_setprio(0);
    __builtin_amdgcn_sched_barrier(0);
    cur ^= 1;
  }

  __syncthreads();

  // ---- epilogue ----
  float w2c[4];
#pragma unroll
  for (int n = 0; n < 4; ++n) w2c[n] = w2[col0 + wc * 64 + n * 16 + r16];

  float rmin[8][4], cmin[4];
#pragma unroll
  for (int m = 0; m < 8; ++m)
#pragma unroll
    for (int j = 0; j < 4; ++j) rmin[m][j] = 1e30f;
#pragma unroll
  for (int n = 0; n < 4; ++n) cmin[n] = 1e30f;

#pragma unroll
  for (int m = 0; m < 8; ++m) {
    int grow = row0 + wr * 128 + m * 16 + q * 4;
#pragma unroll
    for (int n = 0; n < 4; ++n) {
      int gcol = col0 + wc * 64 + n * 16 + r16;
      f32x4 c = acc[m][n];
#pragma unroll
      for (int j = 0; j < 4; ++j) {
        float v = c[j];
        Cout[(size_t)(grow + j) * P_DIM + gcol] = v;
        float d2 = fmaxf(fmaf(-2.0f, v, 1.0f + w2c[n]), 0.0f);
        rmin[m][j] = fminf(rmin[m][j], d2);
        cmin[n] = fminf(cmin[n], d2);
      }
    }
  }
#pragma unroll
  for (int mask = 1; mask <= 8; mask <<= 1)
#pragma unroll
    for (int m = 0; m < 8; ++m)
#pragma unroll
      for (int j = 0; j < 4; ++j)
        rmin[m][j] = fminf(rmin[m][j], __shfl_xor(rmin[m][j], mask));
  if (r16 == 0) {
#pragma unroll
    for (int m = 0; m < 8; ++m)
#pragma unroll
      for (int j = 0; j < 4; ++j)
        atomicMin(&rowmin_u[wr * 128 + m * 16 + q * 4 + j], __float_as_uint(rmin[m][j]));
  }
#pragma unroll
  for (int mask = 16; mask <= 32; mask <<= 1)
#pragma unroll
    for (int n = 0; n < 4; ++n)
      cmin[n] = fminf(cmin[n], __shfl_xor(cmin[n], mask));
  if (q == 0) {
#pragma unroll
    for (int n = 0; n < 4; ++n)
      atomicMin(&colmin_u[wc * 64 + n * 16 + r16], __float_as_uint(cmin[n]));
  }
  __syncthreads();
  if (tid < 256) row_part[(size_t)tn * N_ROWS + row0 + tid] = __uint_as_float(rowmin_u[tid]);
  else           col_part[(size_t)tm * P_DIM + col0 + (tid - 256)] = __uint_as_float(colmin_u[tid - 256]);
}

// ---------------------------------------------------------------------------
__global__ __launch_bounds__(256) void minsqrt_sum(const float* __restrict__ part,
                                                   int nparts, int stride,
                                                   float* __restrict__ out) {
  int idx = blockIdx.x * 256 + threadIdx.x;
  float m = 1e30f;
  for (int p = 0; p < nparts; ++p) m = fminf(m, part[(size_t)p * stride + idx]);
  float s = sqrtf(m);
#pragma unroll
  for (int mask = 1; mask < 64; mask <<= 1) s += __shfl_xor(s, mask);
  __shared__ float wsum[4];
  int wave = threadIdx.x >> 6, lane = threadIdx.x & 63;
  if (lane == 0) wsum[wave] = s;
  __syncthreads();
  if (threadIdx.x == 0) out[blockIdx.x] = wsum[0] + wsum[1] + wsum[2] + wsum[3];
}

__global__ void finalize_kernel(const float* __restrict__ rowp, const float* __restrict__ colp,
                                const float* __restrict__ recon, const float* __restrict__ kl,
                                const float* __restrict__ mmd, float* __restrict__ out) {
  int lane = threadIdx.x;  // 64 threads
  float rs = rowp[lane] + rowp[lane + 64];
  float cs = (lane < 16) ? colp[lane] : 0.0f;
#pragma unroll
  for (int mask = 1; mask < 64; mask <<= 1) {
    rs += __shfl_xor(rs, mask);
    cs += __shfl_xor(cs, mask);
  }
  if (lane == 0) {
    out[OUT_CVAE] = recon[0] + 0.5f * kl[0] + mmd[0];
    out[OUT_PROT] = 0.5f * (rs / (float)N_ROWS) + 0.5f * (cs / (float)P_DIM);
  }
}

extern "C" void kernel_launch(void* const* d_in, const int* in_sizes, int n_in,
                              void* d_out, int out_size, void* d_ws, size_t ws_size,
                              hipStream_t stream) {
  const float* x     = (const float*)d_in[0];
  const float* W     = (const float*)d_in[1];
  const float* recon = (const float*)d_in[2];
  const float* kl    = (const float*)d_in[3];
  const float* mmd   = (const float*)d_in[4];
  float* out    = (float*)d_out;
  float* xn     = out;
  float* logits = out + OUT_LOGITS;

  char* ws = (char*)d_ws;
  unsigned short* Abf = (unsigned short*)ws;                 // 33,554,432 B
  unsigned short* Bbf = (unsigned short*)(ws + 33554432);    //  4,194,304 B
  float* w2       = (float*)(ws + 37748736);                 //     16,384 B
  float* row_part = (float*)(ws + 37765120);                 //  2,097,152 B (16 x 32768)
  float* col_part = (float*)(ws + 39862272);                 //  2,097,152 B (128 x 4096)
  float* rowsums  = (float*)(ws + 41959424);                 //        512 B
  float* colsums  = (float*)(ws + 41959936);                 //         64 B

  prep_kernel<1><<<N_ROWS / 4, 256, 0, stream>>>(x, xn, Abf, nullptr);
  prep_kernel<0><<<P_DIM / 4, 256, 0, stream>>>(W, nullptr, Bbf, w2);
  gemm_fused<<<(N_ROWS / 256) * (P_DIM / 256), 512, 0, stream>>>(
      Abf, Bbf, w2, logits, row_part, col_part);
  minsqrt_sum<<<N_ROWS / 256, 256, 0, stream>>>(row_part, 16, N_ROWS, rowsums);
  minsqrt_sum<<<P_DIM / 256, 256, 0, stream>>>(col_part, 128, P_DIM, colsums);
  finalize_kernel<<<1, 64, 0, stream>>>(rowsums, colsums, recon, kl, mmd, out);
}

// Round 3
// 368.505 us; speedup vs baseline: 1.2866x; 1.0246x over previous
//
#include <hip/hip_runtime.h>

#define N_ROWS 32768
#define D_DIM  512
#define P_DIM  4096

#define OUT_LOGITS (32768LL * 512)
#define OUT_CVAE   (OUT_LOGITS + 32768LL * 4096)
#define OUT_PROT   (OUT_CVAE + 1)

typedef __attribute__((ext_vector_type(8))) short short8;
typedef __attribute__((ext_vector_type(4))) float f32x4;

__device__ __forceinline__ unsigned short f2bf(float f) {
  unsigned u = __float_as_uint(f);
  u = (u + 0x7FFFu + ((u >> 16) & 1u)) >> 16;
  return (unsigned short)u;
}

__device__ __forceinline__ void gload16(const void* g, void* l) {
  __builtin_amdgcn_global_load_lds((const __attribute__((address_space(1))) void*)g,
                                   (__attribute__((address_space(3))) void*)l,
                                   16, 0, 0);
}

// ---------------------------------------------------------------------------
// Prep: row L2-norm; writes bf16 copy in MFMA-fragment-major tiled layout
// (byte-identical to the R1/R2 verified layout):
// elem[(tile*16 + kt32)*8192 + (m*64 + kq*16 + lrow)*8 + e]
// where row = tile*256 + m*16 + lrow, k = kt32*32 + kq*8 + e.
// One wave per row; lane j holds k = j*8..j*8+7.
// ---------------------------------------------------------------------------
template <int NORM>
__global__ __launch_bounds__(256) void prep_kernel(const float* __restrict__ in,
                                                   float* __restrict__ outf,
                                                   unsigned short* __restrict__ outb,
                                                   float* __restrict__ n2) {
  int wave = threadIdx.x >> 6, lane = threadIdx.x & 63;
  int row  = blockIdx.x * 4 + wave;
  const float* p = in + (size_t)row * D_DIM + lane * 8;
  float4 v0 = *(const float4*)p;
  float4 v1 = *(const float4*)(p + 4);
  float ss = v0.x*v0.x + v0.y*v0.y + v0.z*v0.z + v0.w*v0.w
           + v1.x*v1.x + v1.y*v1.y + v1.z*v1.z + v1.w*v1.w;
#pragma unroll
  for (int m = 1; m < 64; m <<= 1) ss += __shfl_xor(ss, m);
  if (NORM) {
    float rinv = 1.0f / fmaxf(sqrtf(ss), 1e-12f);
    v0.x *= rinv; v0.y *= rinv; v0.z *= rinv; v0.w *= rinv;
    v1.x *= rinv; v1.y *= rinv; v1.z *= rinv; v1.w *= rinv;
    float4* qp = (float4*)(outf + (size_t)row * D_DIM + lane * 8);
    qp[0] = v0; qp[1] = v1;
  } else {
    if (lane == 0) n2[row] = ss;
  }
  uint4 b;
  b.x = (unsigned)f2bf(v0.x) | ((unsigned)f2bf(v0.y) << 16);
  b.y = (unsigned)f2bf(v0.z) | ((unsigned)f2bf(v0.w) << 16);
  b.z = (unsigned)f2bf(v1.x) | ((unsigned)f2bf(v1.y) << 16);
  b.w = (unsigned)f2bf(v1.z) | ((unsigned)f2bf(v1.w) << 16);
  int tile = row >> 8, mloc = (row >> 4) & 15, lrow = row & 15;
  size_t dst = ((size_t)(tile * 8 + (lane >> 3)) << 14)
             + (size_t)((((((lane >> 2) & 1) * 16 + mloc) * 64) + (lane & 3) * 16 + lrow) * 8);
  *(uint4*)(outb + dst) = b;
}

// ---------------------------------------------------------------------------
// 256x256-tile GEMM, BK=32, 8 waves (2Mx4N), QUAD-buffered LDS (4 x 32 KiB),
// spread staging (2 gloads/phase), counted vmcnt(8) once per K-tile (never 0
// in steady state), 2 phases/K-tile, setprio around MFMA, no sched_barrier.
// WAR-safe by construction: buffer written at kt = buffer last read at kt-1.
// Epilogue: fp32 logits + fused row/col min of d2 = 1 + |W_j|^2 - 2*logit.
// ---------------------------------------------------------------------------
__global__ __launch_bounds__(512) void gemm_fused(
    const unsigned short* __restrict__ A, const unsigned short* __restrict__ B,
    const float* __restrict__ w2, float* __restrict__ Cout,
    float* __restrict__ row_part, float* __restrict__ col_part) {
  __shared__ __align__(16) unsigned short S[4][16384];   // [buf][A 8192 | B 8192]
  __shared__ unsigned int rowmin_u[256];
  __shared__ unsigned int colmin_u[256];

  const int tid = threadIdx.x;
  const int wave = tid >> 6, lane = tid & 63;
  const int q = lane >> 4, r16 = lane & 15;
  const int wr = wave >> 2, wc = wave & 3;

  int bid = blockIdx.x;
  int swz = ((bid & 7) << 8) | (bid >> 3);          // bijective: 2048 % 8 == 0
  const int tm = swz >> 4, tn = swz & 15;
  const int row0 = tm * 256, col0 = tn * 256;

  if (tid < 256) { rowmin_u[tid] = 0x7F800000u; colmin_u[tid] = 0x7F800000u; }

  const unsigned short* Ab = A + (size_t)tm * 131072;   // 16 kt * 8192 elems
  const unsigned short* Bb = B + (size_t)tn * 131072;

  f32x4 acc[8][4];
#pragma unroll
  for (int m = 0; m < 8; ++m)
#pragma unroll
    for (int n = 0; n < 4; ++n) acc[m][n] = (f32x4){0.f, 0.f, 0.f, 0.f};

  // stage pass p (0/1) of K-tile kt into buffer b: 2 gloads/thread.
  auto stg = [&](int kt, int b, int p) {
    int c = (tid + p * 512) * 8;
    gload16(Ab + (size_t)kt * 8192 + c, &S[b][0] + c);
    gload16(Bb + (size_t)kt * 8192 + c, &S[b][8192] + c);
  };

  // prologue: 3 K-tiles in flight (12 loads); wait first (depth stays >= 8).
  stg(0, 0, 0); stg(0, 0, 1);
  stg(1, 1, 0); stg(1, 1, 1);
  stg(2, 2, 0); stg(2, 2, 1);
  asm volatile("s_waitcnt vmcnt(8)" ::: "memory");
  __builtin_amdgcn_s_barrier();

#pragma unroll
  for (int kt = 0; kt < 16; ++kt) {
    const int cb = kt & 3, sb = (kt + 3) & 3;
    const unsigned short* al = &S[cb][0];
    const unsigned short* bl = &S[cb][8192];
    short8 afr[4], bfr[4], afr2[4];

    // ---- phase 0: reads (8 x ds_read_b128) + stage pass0; MFMA m0-3 x n0-3
#pragma unroll
    for (int m = 0; m < 4; ++m)
      afr[m] = *(const short8*)(al + ((wr * 8 + m) * 64 + lane) * 8);
#pragma unroll
    for (int n = 0; n < 4; ++n)
      bfr[n] = *(const short8*)(bl + ((wc * 4 + n) * 64 + lane) * 8);
    if (kt < 13) stg(kt + 3, sb, 0);
    __builtin_amdgcn_s_barrier();
    asm volatile("s_waitcnt lgkmcnt(0)" ::: "memory");
    __builtin_amdgcn_s_setprio(1);
#pragma unroll
    for (int m = 0; m < 4; ++m)
#pragma unroll
      for (int n = 0; n < 4; ++n)
        acc[m][n] = __builtin_amdgcn_mfma_f32_16x16x32_bf16(afr[m], bfr[n], acc[m][n], 0, 0, 0);
    __builtin_amdgcn_s_setprio(0);
    __builtin_amdgcn_s_barrier();

    // ---- phase 1: reads (4) + stage pass1 + counted vmcnt; MFMA m4-7 x n0-3
#pragma unroll
    for (int m = 0; m < 4; ++m)
      afr2[m] = *(const short8*)(al + ((wr * 8 + 4 + m) * 64 + lane) * 8);
    if (kt < 13) stg(kt + 3, sb, 1);
    // guarantee stage(kt+1) landed (issued during kt-1): newest 8 = kt+2,kt+3.
    if (kt <= 12)      { asm volatile("s_waitcnt vmcnt(8)" ::: "memory"); }
    else if (kt == 13) { asm volatile("s_waitcnt vmcnt(4)" ::: "memory"); }
    else               { asm volatile("s_waitcnt vmcnt(0)" ::: "memory"); }
    __builtin_amdgcn_s_barrier();
    asm volatile("s_waitcnt lgkmcnt(0)" ::: "memory");
    __builtin_amdgcn_s_setprio(1);
#pragma unroll
    for (int m = 0; m < 4; ++m)
#pragma unroll
      for (int n = 0; n < 4; ++n)
        acc[4 + m][n] = __builtin_amdgcn_mfma_f32_16x16x32_bf16(afr2[m], bfr[n], acc[4 + m][n], 0, 0, 0);
    __builtin_amdgcn_s_setprio(0);
    __builtin_amdgcn_s_barrier();
  }

  // ---- epilogue ----
  float w2c[4];
#pragma unroll
  for (int n = 0; n < 4; ++n) w2c[n] = w2[col0 + wc * 64 + n * 16 + r16];

  float rmin[8][4], cmin[4];
#pragma unroll
  for (int m = 0; m < 8; ++m)
#pragma unroll
    for (int j = 0; j < 4; ++j) rmin[m][j] = 1e30f;
#pragma unroll
  for (int n = 0; n < 4; ++n) cmin[n] = 1e30f;

#pragma unroll
  for (int m = 0; m < 8; ++m) {
    int grow = row0 + wr * 128 + m * 16 + q * 4;
#pragma unroll
    for (int n = 0; n < 4; ++n) {
      int gcol = col0 + wc * 64 + n * 16 + r16;
      f32x4 c = acc[m][n];
#pragma unroll
      for (int j = 0; j < 4; ++j) {
        float v = c[j];
        Cout[(size_t)(grow + j) * P_DIM + gcol] = v;
        float d2 = fmaxf(fmaf(-2.0f, v, 1.0f + w2c[n]), 0.0f);
        rmin[m][j] = fminf(rmin[m][j], d2);
        cmin[n] = fminf(cmin[n], d2);
      }
    }
  }
#pragma unroll
  for (int mask = 1; mask <= 8; mask <<= 1)
#pragma unroll
    for (int m = 0; m < 8; ++m)
#pragma unroll
      for (int j = 0; j < 4; ++j)
        rmin[m][j] = fminf(rmin[m][j], __shfl_xor(rmin[m][j], mask));
  if (r16 == 0) {
#pragma unroll
    for (int m = 0; m < 8; ++m)
#pragma unroll
      for (int j = 0; j < 4; ++j)
        atomicMin(&rowmin_u[wr * 128 + m * 16 + q * 4 + j], __float_as_uint(rmin[m][j]));
  }
#pragma unroll
  for (int mask = 16; mask <= 32; mask <<= 1)
#pragma unroll
    for (int n = 0; n < 4; ++n)
      cmin[n] = fminf(cmin[n], __shfl_xor(cmin[n], mask));
  if (q == 0) {
#pragma unroll
    for (int n = 0; n < 4; ++n)
      atomicMin(&colmin_u[wc * 64 + n * 16 + r16], __float_as_uint(cmin[n]));
  }
  __syncthreads();
  if (tid < 256) row_part[(size_t)tn * N_ROWS + row0 + tid] = __uint_as_float(rowmin_u[tid]);
  else           col_part[(size_t)tm * P_DIM + col0 + (tid - 256)] = __uint_as_float(colmin_u[tid - 256]);
}

// ---------------------------------------------------------------------------
__global__ __launch_bounds__(256) void minsqrt_sum(const float* __restrict__ part,
                                                   int nparts, int stride,
                                                   float* __restrict__ out) {
  int idx = blockIdx.x * 256 + threadIdx.x;
  float m = 1e30f;
  for (int p = 0; p < nparts; ++p) m = fminf(m, part[(size_t)p * stride + idx]);
  float s = sqrtf(m);
#pragma unroll
  for (int mask = 1; mask < 64; mask <<= 1) s += __shfl_xor(s, mask);
  __shared__ float wsum[4];
  int wave = threadIdx.x >> 6, lane = threadIdx.x & 63;
  if (lane == 0) wsum[wave] = s;
  __syncthreads();
  if (threadIdx.x == 0) out[blockIdx.x] = wsum[0] + wsum[1] + wsum[2] + wsum[3];
}

__global__ void finalize_kernel(const float* __restrict__ rowp, const float* __restrict__ colp,
                                const float* __restrict__ recon, const float* __restrict__ kl,
                                const float* __restrict__ mmd, float* __restrict__ out) {
  int lane = threadIdx.x;  // 64 threads
  float rs = rowp[lane] + rowp[lane + 64];
  float cs = (lane < 16) ? colp[lane] : 0.0f;
#pragma unroll
  for (int mask = 1; mask < 64; mask <<= 1) {
    rs += __shfl_xor(rs, mask);
    cs += __shfl_xor(cs, mask);
  }
  if (lane == 0) {
    out[OUT_CVAE] = recon[0] + 0.5f * kl[0] + mmd[0];
    out[OUT_PROT] = 0.5f * (rs / (float)N_ROWS) + 0.5f * (cs / (float)P_DIM);
  }
}

extern "C" void kernel_launch(void* const* d_in, const int* in_sizes, int n_in,
                              void* d_out, int out_size, void* d_ws, size_t ws_size,
                              hipStream_t stream) {
  const float* x     = (const float*)d_in[0];
  const float* W     = (const float*)d_in[1];
  const float* recon = (const float*)d_in[2];
  const float* kl    = (const float*)d_in[3];
  const float* mmd   = (const float*)d_in[4];
  float* out    = (float*)d_out;
  float* xn     = out;
  float* logits = out + OUT_LOGITS;

  char* ws = (char*)d_ws;
  unsigned short* Abf = (unsigned short*)ws;                 // 33,554,432 B
  unsigned short* Bbf = (unsigned short*)(ws + 33554432);    //  4,194,304 B
  float* w2       = (float*)(ws + 37748736);                 //     16,384 B
  float* row_part = (float*)(ws + 37765120);                 //  2,097,152 B (16 x 32768)
  float* col_part = (float*)(ws + 39862272);                 //  2,097,152 B (128 x 4096)
  float* rowsums  = (float*)(ws + 41959424);                 //        512 B
  float* colsums  = (float*)(ws + 41959936);                 //         64 B

  prep_kernel<1><<<N_ROWS / 4, 256, 0, stream>>>(x, xn, Abf, nullptr);
  prep_kernel<0><<<P_DIM / 4, 256, 0, stream>>>(W, nullptr, Bbf, w2);
  gemm_fused<<<(N_ROWS / 256) * (P_DIM / 256), 512, 0, stream>>>(
      Abf, Bbf, w2, logits, row_part, col_part);
  minsqrt_sum<<<N_ROWS / 256, 256, 0, stream>>>(row_part, 16, N_ROWS, rowsums);
  minsqrt_sum<<<P_DIM / 256, 256, 0, stream>>>(col_part, 128, P_DIM, colsums);
  finalize_kernel<<<1, 64, 0, stream>>>(rowsums, colsums, recon, kl, mmd, out);
}